// Round 8
// baseline (176.191 us; speedup 1.0000x reference)
//
#include <hip/hip_runtime.h>
#include <hip/hip_bf16.h>

#define BATCH 32768
#define NF    64              // fields (K and N of the GEMM)
#define NE    12              // embedding dim
#define MB    8               // batch rows per tile
#define MROWS (MB*NE)         // 96 M-rows per tile (6 m-subtiles)
#define NTHR  192             // 3 waves, 2 m-subtiles each
#define NTILE (BATCH/MB)      // 4096
#define GRID  1024
#define TPB   (NTILE/GRID)    // 4 tiles per block

typedef __attribute__((ext_vector_type(8))) short short8;   // 8 bf16 = 4 VGPR
typedef __attribute__((ext_vector_type(4))) float float4v;

// d_ws: ShT bf16[64][64] @0 | SlT @8KB | WT f32[12][64] @16KB
#define WS_SHT 0
#define WS_SLT 8192
#define WS_WT  16384

#define GLOBAL_AS __attribute__((address_space(1)))
#define LDS_AS    __attribute__((address_space(3)))

__device__ __forceinline__ short bfb(float v) {
    union { __hip_bfloat16 h; short s; } u;
    u.h = __float2bfloat16(v);
    return u.s;
}

// K-slot permutation: within a K=32 block, slot s = q*8+j holds i_local =
// 4*j + q.  Applied to BOTH the A-frag ds_reads and the prep-stored S^T, so
// dot products are unchanged; it spreads the 4 q-quadrants across LDS banks
// (natural layout would put all q at identical banks: 96*12 = 0 mod 32).
__global__ void prep_kernel(const float* __restrict__ V, const float* __restrict__ W,
                            unsigned short* __restrict__ ShT,
                            unsigned short* __restrict__ SlT,
                            float* __restrict__ WT) {
    const int idx = blockIdx.x * 256 + threadIdx.x;   // 0..4095
    if (idx < NF * NF) {
        const int n  = idx >> 6, ks = idx & 63;
        const int kb = ks >> 5,  s  = ks & 31;
        const int i  = (kb << 5) + ((s & 7) << 2) + (s >> 3);   // permuted K index
        const float4v a = *(const float4v*)(V + (size_t)((i << 6) | n) * 4);
        const float4v b = *(const float4v*)(V + (size_t)((n << 6) | i) * 4);
        const float sv = (i == n) ? 0.0f
                       : 0.5f * (a.x * b.x + a.y * b.y + a.z * b.z + a.w * b.w);
        const __hip_bfloat16 sh = __float2bfloat16(sv);
        union { __hip_bfloat16 h; unsigned short u; } uh, ul;
        uh.h = sh; ul.h = __float2bfloat16(sv - __bfloat162float(sh));
        ShT[idx] = uh.u;    // [n][k-slot]
        SlT[idx] = ul.u;
    }
    if (idx < NF * NE) {
        const int j = idx / NE, e = idx - j * NE;
        WT[e * 64 + j] = W[idx];
    }
}

// async DMA of one 24KB tile (natural layout) into LDS: 24 x 1KB insts, 8/wave
__device__ __forceinline__ void dma_tile(const float* __restrict__ x, int tile,
                                         float* dst, int w, int lane) {
    const float4v* src = (const float4v*)(x + (size_t)tile * MB * (NF * NE));
    #pragma unroll
    for (int k2 = 0; k2 < 8; ++k2) {
        const int k = w * 8 + k2;
        const float4v* g = src + k * 64 + lane;
        float* l = dst + k * 256 + lane * 4;
        __builtin_amdgcn_global_load_lds((const GLOBAL_AS void*)g,
                                         (LDS_AS void*)l, 16, 0, 0);
    }
}

// Double-buffered pipeline, one barrier per tile:
//   sync(drains DMA t) -> issue DMA(t+1, other buf) -> store out(t-1) -> compute(t)
__global__ __launch_bounds__(NTHR, 3) void ffm_mfma(
    const float* __restrict__ x,
    const float* __restrict__ bvec,
    const unsigned short* __restrict__ ShT,
    const unsigned short* __restrict__ SlT,
    const float* __restrict__ WT,
    float* __restrict__ out)
{
    __shared__ float Xs[2][MB * NF * NE];   // 2 x 24 KB, natural [b][i][e]
    __shared__ float red[2][MROWS];

    const int tid  = threadIdx.x;
    const int w    = tid >> 6;
    const int lane = tid & 63;
    const int l15  = lane & 15;
    const int q    = lane >> 4;

    // resident S fragments: B[k-slot][n=l15], permuted layout from prep
    short8 shf[4][2], slf[4][2];
    #pragma unroll
    for (int ns = 0; ns < 4; ++ns)
        #pragma unroll
        for (int kb = 0; kb < 2; ++kb) {
            const int off = ((ns << 4) + l15) * 64 + kb * 32 + q * 8;
            shf[ns][kb] = *(const short8*)(ShT + off);
            slf[ns][kb] = *(const short8*)(SlT + off);
        }

    dma_tile(x, blockIdx.x, Xs[0], w, lane);   // tile 0 -> buf 0

    for (int tt = 0; tt < TPB; ++tt) {
        __syncthreads();   // drains this wave's DMA (vmcnt 0) + joins prev compute
        const int buf = tt & 1;

        if (tt + 1 < TPB)
            dma_tile(x, (tt + 1) * GRID + blockIdx.x, Xs[buf ^ 1], w, lane);

        if (tt > 0 && tid < MB) {   // tile tt-1 output from red[buf^1]
            float s = 0.0f;
            #pragma unroll
            for (int e = 0; e < NE; ++e) s += red[buf ^ 1][tid * NE + e];
            const float z = s + bvec[0];
            out[((tt - 1) * GRID + blockIdx.x) * MB + tid] = 1.0f / (1.0f + __expf(-z));
        }

        const float* Xb = Xs[buf];
        #pragma unroll
        for (int ms = 0; ms < 2; ++ms) {
            const int msg = w * 2 + ms;            // m-subtile 0..5
            {
                const int m = (msg << 4) + l15;    // A row
                const int b = m / NE, e = m - (m / NE) * NE;
                const float* abase = Xb + b * (NF * NE) + e + q * NE;  // + i*12 via imm

                short8 ah[2], al[2];
                #pragma unroll
                for (int kb = 0; kb < 2; ++kb)
                    #pragma unroll
                    for (int j = 0; j < 8; ++j) {
                        // k-slot q*8+j  ->  i = kb*32 + 4*j + q
                        const float vv = abase[(kb * 32 + 4 * j) * NE];
                        const __hip_bfloat16 h = __float2bfloat16(vv);
                        ah[kb][j] = bfb(vv);
                        al[kb][j] = bfb(vv - __bfloat162float(h));
                    }

                float4v acc[4];
                #pragma unroll
                for (int ns = 0; ns < 4; ++ns) {
                    float4v c = (float4v){0.f, 0.f, 0.f, 0.f};
                    c = __builtin_amdgcn_mfma_f32_16x16x32_bf16(ah[0], shf[ns][0], c, 0, 0, 0);
                    c = __builtin_amdgcn_mfma_f32_16x16x32_bf16(ah[1], shf[ns][1], c, 0, 0, 0);
                    c = __builtin_amdgcn_mfma_f32_16x16x32_bf16(al[0], shf[ns][0], c, 0, 0, 0);
                    c = __builtin_amdgcn_mfma_f32_16x16x32_bf16(al[1], shf[ns][1], c, 0, 0, 0);
                    c = __builtin_amdgcn_mfma_f32_16x16x32_bf16(ah[0], slf[ns][0], c, 0, 0, 0);
                    c = __builtin_amdgcn_mfma_f32_16x16x32_bf16(ah[1], slf[ns][1], c, 0, 0, 0);
                    acc[ns] = c;
                }

                // fused epilogue: P[m'] = sum_n A_f32[m'][n]*(C[m'][n]+WT[e][n])
                // C/D: col n = l15, row m' = q*4+rg (within subtile)
                #pragma unroll
                for (int rg = 0; rg < 4; ++rg) {
                    const int mm = (msg << 4) + (q << 2) + rg;
                    const int bb2 = mm / NE, ee = mm - bb2 * NE;
                    const float* ebase = Xb + bb2 * (NF * NE) + ee + l15 * NE;
                    float p = 0.0f;
                    #pragma unroll
                    for (int ns = 0; ns < 4; ++ns) {
                        const int n = (ns << 4) + l15;
                        p = fmaf(ebase[(ns << 4) * NE], acc[ns][rg] + WT[ee * 64 + n], p);
                    }
                    p += __shfl_xor(p, 1);
                    p += __shfl_xor(p, 2);
                    p += __shfl_xor(p, 4);
                    p += __shfl_xor(p, 8);
                    if (l15 == 0) red[buf][mm] = p;
                }
            }
        }
    }

    __syncthreads();
    if (tid < MB) {   // last tile's output
        const int buf = (TPB - 1) & 1;
        float s = 0.0f;
        #pragma unroll
        for (int e = 0; e < NE; ++e) s += red[buf][tid * NE + e];
        const float z = s + bvec[0];
        out[((TPB - 1) * GRID + blockIdx.x) * MB + tid] = 1.0f / (1.0f + __expf(-z));
    }
}

extern "C" void kernel_launch(void* const* d_in, const int* in_sizes, int n_in,
                              void* d_out, int out_size, void* d_ws, size_t ws_size,
                              hipStream_t stream) {
    const float* x  = (const float*)d_in[0];
    const float* W  = (const float*)d_in[1];  // [1,768]
    const float* bb = (const float*)d_in[2];  // [1]
    const float* V  = (const float*)d_in[3];  // [64,64,4]
    unsigned short* ShT = (unsigned short*)((char*)d_ws + WS_SHT);
    unsigned short* SlT = (unsigned short*)((char*)d_ws + WS_SLT);
    float*          WT  = (float*)((char*)d_ws + WS_WT);
    float* out = (float*)d_out;

    prep_kernel<<<dim3(16), dim3(256), 0, stream>>>(V, W, ShT, SlT, WT);
    ffm_mfma<<<dim3(GRID), dim3(NTHR), 0, stream>>>(x, bb, ShT, SlT, WT, out);
}

// Round 9
// 156.593 us; speedup vs baseline: 1.1251x; 1.1251x over previous
//
#include <hip/hip_runtime.h>
#include <hip/hip_bf16.h>

#define BATCH 32768
#define NF    64              // fields (K of the GEMM)
#define NE    12              // embedding dim
#define NEXT  80              // extended N: 64 S-cols + 12 W-cols + 4 zero
#define MB    16              // batch rows per tile
#define MROWS (MB*NE)         // 192 M-rows per tile (12 subtiles)
#define LSTR  68              // LDS f32 row stride (64+4 pad)
#define NBLK  (BATCH/MB)      // 2048

typedef __attribute__((ext_vector_type(8))) short short8;
typedef __attribute__((ext_vector_type(4))) float float4v;

// d_ws: BhT bf16[80][64] @0 (10KB) | BlT bf16[80][64] @10240
#define WS_BHT 0
#define WS_BLT 10240

__device__ __forceinline__ short bfb(float v) {
    union { __hip_bfloat16 h; short s; } u;
    u.h = __float2bfloat16(v);
    return u.s;
}

// ---- prep: Bext[k][n] = { n<64: (k==n?0:0.5*<V[k,n],V[n,k]>) ;
//                           64<=n<76: W[k*12+(n-64)] ; else 0 }
// split bf16 hi/lo, stored transposed [n][k].
__global__ void prep_kernel(const float* __restrict__ V, const float* __restrict__ W,
                            unsigned short* __restrict__ BhT,
                            unsigned short* __restrict__ BlT) {
    const int idx = blockIdx.x * 256 + threadIdx.x;   // 0..5119
    if (idx >= NEXT * NF) return;
    const int n = idx >> 6, k = idx & 63;
    float v = 0.0f;
    if (n < 64) {
        if (k != n) {
            const float4v a = *(const float4v*)(V + (size_t)((k << 6) | n) * 4);
            const float4v b = *(const float4v*)(V + (size_t)((n << 6) | k) * 4);
            v = 0.5f * (a.x * b.x + a.y * b.y + a.z * b.z + a.w * b.w);
        }
    } else if (n < 76) {
        v = W[k * NE + (n - 64)];
    }
    const __hip_bfloat16 h = __float2bfloat16(v);
    union { __hip_bfloat16 h; unsigned short u; } uh, ul;
    uh.h = h; ul.h = __float2bfloat16(v - __bfloat162float(h));
    BhT[idx] = uh.u;
    BlT[idx] = ul.u;
}

// Per tile: Y2 = A(192x64, split bf16) x Bext(64x80); Y1 = A x I (exact, via
// MFMA -> A in C-layout).  p_m = sum_n Y1[m,n]*Y2[m,n] + Y2[m,64+e(m)] —
// pure register epilogue, no LDS re-read of A.
__global__ __launch_bounds__(256, 3) void ffm_mfma(
    const float* __restrict__ x,
    const float* __restrict__ bvec,
    const unsigned short* __restrict__ BhT,
    const unsigned short* __restrict__ BlT,
    float* __restrict__ out)
{
    __shared__ float Xs[MROWS * LSTR];   // 51 KB, [(b,e)][i] f32
    __shared__ float red[MROWS];

    const int tid  = threadIdx.x;
    const int w    = tid >> 6;
    const int lane = tid & 63;
    const int l15  = lane & 15;
    const int q    = lane >> 4;

    // ---- phase 1: issue the 12 global x loads first (HBM long pole)
    const float4v* xg = (const float4v*)(x + (size_t)blockIdx.x * MB * (NF * NE));
    float4v v[12];
    #pragma unroll
    for (int p = 0; p < 12; ++p) v[p] = xg[p * 256 + tid];

    // ---- resident B fragments: B[k=kb*32+q*8+j][n=ns*16+l15] (L2-hot table)
    short8 shf[5][2], slf[5][2];
    #pragma unroll
    for (int ns = 0; ns < 5; ++ns)
        #pragma unroll
        for (int kb = 0; kb < 2; ++kb) {
            const int off = ((ns << 4) + l15) * 64 + kb * 32 + q * 8;
            shf[ns][kb] = *(const short8*)(BhT + off);
            slf[ns][kb] = *(const short8*)(BlT + off);
        }

    // identity B-frags (bf16 1.0 = 0x3F80): If[h][j] = (q*8+j == h*16+l15)
    short8 If[2];
    #pragma unroll
    for (int h = 0; h < 2; ++h)
        #pragma unroll
        for (int j = 0; j < 8; ++j)
            If[h][j] = (q * 8 + j == h * 16 + l15) ? (short)0x3F80 : (short)0;

    // ---- phase 2: scatter x tile to LDS transposed [(b,e)][i]
    #pragma unroll
    for (int p = 0; p < 12; ++p) {
        const int fid = p * 256 + tid;
        const int b   = fid / 192;
        const int c4  = fid - b * 192;
        const int d0  = c4 * 4;
        const int i0  = d0 / 12;
        const int e0  = d0 - i0 * 12;         // in {0,4,8}
        float* dst = Xs + (b * NE + e0) * LSTR + i0;
        dst[0 * LSTR] = v[p].x; dst[1 * LSTR] = v[p].y;
        dst[2 * LSTR] = v[p].z; dst[3 * LSTR] = v[p].w;
    }
    __syncthreads();

    #pragma unroll
    for (int ms = 0; ms < 3; ++ms) {
        const int msg  = w * 3 + ms;           // m-subtile 0..11
        const int mrow = (msg << 4) + l15;     // A row (m = lane&15)

        // A-frag from LDS (b128) -> bf16 hi/lo split
        short8 ah[2], al[2];
        #pragma unroll
        for (int kb = 0; kb < 2; ++kb) {
            const float4v t0 = *(const float4v*)(Xs + mrow * LSTR + kb * 32 + q * 8);
            const float4v t1 = *(const float4v*)(Xs + mrow * LSTR + kb * 32 + q * 8 + 4);
            const float a8[8] = {t0.x, t0.y, t0.z, t0.w, t1.x, t1.y, t1.z, t1.w};
            #pragma unroll
            for (int j = 0; j < 8; ++j) {
                const float vv = a8[j];
                const __hip_bfloat16 h = __float2bfloat16(vv);
                ah[kb][j] = bfb(vv);
                al[kb][j] = bfb(vv - __bfloat162float(h));
            }
        }

        // Y1 = A·I (exact fp32 A in C-layout); diagonal block lives in kb=ns>>1
        float4v y1[4];
        #pragma unroll
        for (int ns = 0; ns < 4; ++ns) {
            const int kb = ns >> 1;
            float4v c = (float4v){0.f, 0.f, 0.f, 0.f};
            c = __builtin_amdgcn_mfma_f32_16x16x32_bf16(ah[kb], If[ns & 1], c, 0, 0, 0);
            c = __builtin_amdgcn_mfma_f32_16x16x32_bf16(al[kb], If[ns & 1], c, 0, 0, 0);
            y1[ns] = c;
        }

        // Y2 = A·Bext (3-product split), 5 n-blocks (last = W columns)
        float pv[4] = {0.f, 0.f, 0.f, 0.f};
        #pragma unroll
        for (int ns = 0; ns < 5; ++ns) {
            float4v c = (float4v){0.f, 0.f, 0.f, 0.f};
            c = __builtin_amdgcn_mfma_f32_16x16x32_bf16(ah[0], shf[ns][0], c, 0, 0, 0);
            c = __builtin_amdgcn_mfma_f32_16x16x32_bf16(ah[1], shf[ns][1], c, 0, 0, 0);
            c = __builtin_amdgcn_mfma_f32_16x16x32_bf16(al[0], shf[ns][0], c, 0, 0, 0);
            c = __builtin_amdgcn_mfma_f32_16x16x32_bf16(al[1], shf[ns][1], c, 0, 0, 0);
            c = __builtin_amdgcn_mfma_f32_16x16x32_bf16(ah[0], slf[ns][0], c, 0, 0, 0);
            c = __builtin_amdgcn_mfma_f32_16x16x32_bf16(ah[1], slf[ns][1], c, 0, 0, 0);
            if (ns < 4) {
                #pragma unroll
                for (int rg = 0; rg < 4; ++rg)
                    pv[rg] = fmaf(y1[ns][rg], c[rg], pv[rg]);
            } else {
                // linear term: row m picks col 64+e(m); owner lane l15==e(m)
                #pragma unroll
                for (int rg = 0; rg < 4; ++rg) {
                    const int m = (msg << 4) + (q << 2) + rg;
                    const int e = m % NE;
                    pv[rg] += (l15 == e) ? c[rg] : 0.0f;
                }
            }
        }

        // reduce over l15 (stays within q-group), write red[m]
        #pragma unroll
        for (int rg = 0; rg < 4; ++rg) {
            float p = pv[rg];
            p += __shfl_xor(p, 1);
            p += __shfl_xor(p, 2);
            p += __shfl_xor(p, 4);
            p += __shfl_xor(p, 8);
            if (l15 == 0) red[(msg << 4) + (q << 2) + rg] = p;
        }
    }
    __syncthreads();

    if (tid < MB) {
        float s = 0.0f;
        #pragma unroll
        for (int e = 0; e < NE; ++e) s += red[tid * NE + e];
        const float z = s + bvec[0];
        out[blockIdx.x * MB + tid] = 1.0f / (1.0f + __expf(-z));
    }
}

extern "C" void kernel_launch(void* const* d_in, const int* in_sizes, int n_in,
                              void* d_out, int out_size, void* d_ws, size_t ws_size,
                              hipStream_t stream) {
    const float* x  = (const float*)d_in[0];
    const float* W  = (const float*)d_in[1];  // [1,768]
    const float* bb = (const float*)d_in[2];  // [1]
    const float* V  = (const float*)d_in[3];  // [64,64,4]
    unsigned short* BhT = (unsigned short*)((char*)d_ws + WS_BHT);
    unsigned short* BlT = (unsigned short*)((char*)d_ws + WS_BLT);
    float* out = (float*)d_out;

    prep_kernel<<<dim3(20), dim3(256), 0, stream>>>(V, W, BhT, BlT);
    ffm_mfma<<<dim3(NBLK), dim3(256), 0, stream>>>(x, bb, BhT, BlT, out);
}